// Round 8
// baseline (158.786 us; speedup 1.0000x reference)
//
#include <hip/hip_runtime.h>

#define DIMC 1024
#define HEADS 16
#define HD 64
#define BATCH 2
#define SEQ 1024
#define NQKV 3072

typedef _Float16 f16;
typedef _Float16 half8 __attribute__((ext_vector_type(8)));
typedef _Float16 half4v __attribute__((ext_vector_type(4)));
typedef float floatx4 __attribute__((ext_vector_type(4)));

__device__ __forceinline__ void gld16(const void* g, void* l) {
  __builtin_amdgcn_global_load_lds((const __attribute__((address_space(1))) void*)g,
                                   (__attribute__((address_space(3))) void*)l, 16, 0, 0);
}

__device__ __forceinline__ unsigned sadU8(unsigned a, unsigned b, unsigned c) {
#if __has_builtin(__builtin_amdgcn_sad_u8)
  return __builtin_amdgcn_sad_u8(a, b, c);
#else
  unsigned d;
  asm("v_sad_u8 %0, %1, %2, %3" : "=v"(d) : "v"(a), "v"(b), "v"(c));
  return d;
#endif
}

// ---------------- f32 -> f16 casts (x, qkv_w, proj_w), 4 float4/thread ----------------
__global__ __launch_bounds__(256) void cvt_kernel(
    const float* __restrict__ x, const float* __restrict__ wq, const float* __restrict__ wp,
    f16* __restrict__ x16, f16* __restrict__ wq16, f16* __restrict__ wp16)
{
  int bid = blockIdx.x;
  const float* src; f16* dst; int base;
  if (bid < 512)        { src = x;  dst = x16;  base = bid; }
  else if (bid < 1280)  { src = wq; dst = wq16; base = bid - 512; }
  else                  { src = wp; dst = wp16; base = bid - 1280; }
  long long i0 = (long long)base*1024 + threadIdx.x;
#pragma unroll
  for (int k2 = 0; k2 < 4; ++k2) {
    long long i = i0 + k2*256;   // float4 index, coalesced
    float4 v = ((const float4*)src)[i];
    half4v h; h[0]=(f16)v.x; h[1]=(f16)v.y; h[2]=(f16)v.z; h[3]=(f16)v.w;
    *(half4v*)(dst + i*4) = h;
  }
}

// ---------------- TM x TN f16 MFMA GEMM (BK-deep K-tiles), C = A * Bw^T + bias ----
// MODE 0: QKV -> q8/k8 (u8 quant, [b,h,s,d]) and vT (f16, [b,h,d,s])
// MODE 1: proj -> f32 out [t, f]
// Proven configs: gemm0 128x128 BK128 MW2, gemm1 64x64 BK128 MW4 (R14/R17
// tiling/residency variations all neutral).
template<int TM, int TN, int BK, int MW, int MODE>
__global__ __launch_bounds__(256, MW) void gemm_kernel(
    const f16* __restrict__ A, const f16* __restrict__ Bw, const float* __restrict__ bias,
    unsigned char* __restrict__ q8, unsigned char* __restrict__ k8, f16* __restrict__ vT,
    float* __restrict__ outp, int K)
{
  constexpr int MT = TM / 32;   // m-subtiles per wave
  constexpr int NT = TN / 32;   // n-subtiles per wave
  constexpr int G  = BK / 8;    // 16B groups per LDS row
  __shared__ f16 As[TM*BK];
  __shared__ f16 Bs[TN*BK];
  const int tid = threadIdx.x;
  const int wave = tid >> 6, lane = tid & 63;
  const int lq = lane >> 4, li = lane & 15;
  const int m0 = blockIdx.y * TM, n0 = blockIdx.x * TN;
  const int wm = (wave & 1) * (TM/2), wn = (wave >> 1) * (TN/2);
  floatx4 acc[MT][NT] = {};

  const int kIters = K / BK;
  for (int kt = 0; kt < kIters; ++kt) {
    __syncthreads();
#pragma unroll
    for (int r = 0; r < TM*BK/2048; ++r) {
      int slot = r*256 + tid;
      int row = slot / G, c = slot % G, g = c ^ (row & (G-1));
      gld16(A + (size_t)(m0+row)*K + kt*BK + g*8, As + slot*8);
    }
#pragma unroll
    for (int r = 0; r < TN*BK/2048; ++r) {
      int slot = r*256 + tid;
      int row = slot / G, c = slot % G, g = c ^ (row & (G-1));
      gld16(Bw + (size_t)(n0+row)*K + kt*BK + g*8, Bs + slot*8);
    }
    __syncthreads();
#pragma unroll
    for (int ks = 0; ks < BK/32; ++ks) {
      half8 af[MT], bf[NT];
      int kc = ks*4 + lq;
#pragma unroll
      for (int t = 0; t < MT; ++t) {
        int am = wm + t*16 + li;
        af[t] = *(const half8*)&As[am*BK + (kc ^ (am & (G-1)))*8];
      }
#pragma unroll
      for (int t = 0; t < NT; ++t) {
        int bn = wn + t*16 + li;
        bf[t] = *(const half8*)&Bs[bn*BK + (kc ^ (bn & (G-1)))*8];
      }
#pragma unroll
      for (int mt = 0; mt < MT; ++mt)
#pragma unroll
        for (int nt = 0; nt < NT; ++nt)
          acc[mt][nt] = __builtin_amdgcn_mfma_f32_16x16x32_f16(af[mt], bf[nt], acc[mt][nt], 0, 0, 0);
    }
  }

#pragma unroll
  for (int mt = 0; mt < MT; ++mt) {
#pragma unroll
    for (int nt = 0; nt < NT; ++nt) {
      int f = n0 + wn + nt*16 + li;                 // output feature (col, from B)
      float bb = bias[f];
      if (MODE == 0) {
        int which = f >> 10, cc = f & 1023, h = cc >> 6, d = cc & 63;
        int t0 = m0 + wm + mt*16 + lq*4;            // token (row, from A), 4 consecutive
        int b = t0 >> 10, s0 = t0 & 1023;
        if (which == 2) {
          half4v hv;
#pragma unroll
          for (int r = 0; r < 4; ++r) hv[r] = (f16)(acc[mt][nt][r] + bb);
          *(half4v*)&vT[((size_t)((b*HEADS + h)*HD + d))*SEQ + s0] = hv;
        } else {
          unsigned char* dst = (which == 0) ? q8 : k8;
#pragma unroll
          for (int r = 0; r < 4; ++r) {
            float v = acc[mt][nt][r] + bb;
            int u = (int)floorf(v * 16.0f + 128.5f);
            u = u < 0 ? 0 : (u > 255 ? 255 : u);
            dst[((size_t)((b*HEADS + h)*SEQ + s0 + r))*HD + d] = (unsigned char)u;
          }
        }
      } else {
#pragma unroll
        for (int r = 0; r < 4; ++r) {
          int t = m0 + wm + mt*16 + lq*4 + r;
          outp[(size_t)t*DIMC + f] = acc[mt][nt][r] + bb;
        }
      }
    }
  }
}

// ---------------- Laplacian attention + depthwise conv, y16 out ----------------
// R20 (on top of R19): phase-1 retile 2i x 8j -> 4i x 4j per thread.
// Evidence: R19 killed conflicts (5.25M->532K) + vTs staging + 8 barriers for
// only -0.8us -> those were secondary. Per-CU LDS-pipe accounting shows kk
// reads (32 b128/thread/jb, 512 of ~670 wave-instrs/CU/jb) are the largest
// single pipe term. 4i x 4j halves kk reads to 16 (SAD count unchanged).
// R15's failure mode avoided: qr stays 64 u32 (the size that provably stays
// resident, R1 VGPR=84), and the new 8-addr kk pattern (rows 4 apart, 256B
// stride) gets chunk swizzle c^((row>>2)&3) -> 4 quads x 2-way (free, m136).
// Diagnostic: neutral result => LDS broadcast reads are cheap, kernel is
// latency-bound -> next arc structural.
__global__ __launch_bounds__(256, 4) void attn_kernel(
    const unsigned char* __restrict__ q8g, const unsigned char* __restrict__ k8g,
    const f16* __restrict__ vTg, const float* __restrict__ dwcw, const float* __restrict__ dwcb,
    f16* __restrict__ y16)
{
  __shared__ unsigned char q8s[32*64];     //  2KB
  __shared__ unsigned char k8s[2][128*64]; // 16KB double-buffered, chunk-swizzled
  __shared__ f16 sfrag[2][8*64*8];         // 16KB double-buffered A-frag scores
  __shared__ float rspart[32*32];          //  4KB [jslice][row]
  __shared__ float rowsum[32];             // total ~39KB -> 4 blocks/CU

  const int tid = threadIdx.x;
  const int lin = blockIdx.x + 16 * blockIdx.y;      // 0..1023
  const int bh = (lin & 7) * 4 + ((lin >> 3) & 3);   // XCD-grouped head index
  const int i0 = (lin >> 5) * 32;                    // 32 i-blocks of 32 rows
  const int lane = tid & 63, wave = tid >> 6;
  const int lq = lane >> 4, li = lane & 15;
  // phase-1 mapping: 4 i-rows x 4 j-cols per thread
  const int iL8 = tid & 7;            // i-rows {iL8 + n*8}, n=0..3
  const int jt5 = tid >> 3;           // 0..31, k-rows {jt5*4 + jj}, jj=0..3
  const int ksj5 = jt5 >> 3;          // PV k-slice (wave-uniform)
  const int lqp  = (jt5 >> 1) & 3;    // A-frag lane-quarter
  const int e0   = (jt5 & 1) * 4;     // elem offset within half8 frag
  const int kswz = jt5 & 3;           // kk chunk-swizzle read key

  { // stage q tile (32x64B, waves 0-1) + k8s[0] with chunk swizzle (row>>2)
    if (tid < 128)
      gld16(q8g + ((size_t)(bh*SEQ) + i0)*HD + tid*16, q8s + tid*16);
#pragma unroll
    for (int r = 0; r < 2; ++r) {
      int slot = r*256 + tid;
      int row = slot >> 2, c4 = slot & 3, sc4 = c4 ^ ((row >> 2) & 3);
      gld16(k8g + ((size_t)(bh*SEQ) + row)*HD + sc4*16, k8s[0] + slot*16);
    }
  }
  __syncthreads();

  // q rows {iL8 + n*8} into regs (64 u32)
  unsigned qr[4][16];
#pragma unroll
  for (int n = 0; n < 4; ++n)
#pragma unroll
    for (int c4 = 0; c4 < 4; ++c4) {
      uint4 t = *(const uint4*)&q8s[(iL8 + n*8)*64 + c4*16];
      qr[n][c4*4+0] = t.x; qr[n][c4*4+1] = t.y; qr[n][c4*4+2] = t.z; qr[n][c4*4+3] = t.w;
    }

  float rs[4] = {};
  floatx4 pacc[2] = {};                  // this wave owns d-strip wave*16..+15
  const f16* vbase = vTg + ((size_t)(bh*HD) + wave*16 + li)*SEQ;

  for (int jb = 0; jb < 8; ++jb) {
    const int j0 = jb * 128;
    const int cur = jb & 1;

    // stage NEXT k tile (consumed in iter jb+1; lands by this iter's barrier)
    if (jb < 7) {
#pragma unroll
      for (int r = 0; r < 2; ++r) {
        int slot = r*256 + tid;
        int row = slot >> 2, c4 = slot & 3, sc4 = c4 ^ ((row >> 2) & 3);
        gld16(k8g + ((size_t)(bh*SEQ) + j0 + 128 + row)*HD + sc4*16,
              k8s[cur ^ 1] + slot*16);
      }
    }
    // issue this iter's V B-frags (global->reg, waited at MFMA use)
    half8 vfrag[4];
#pragma unroll
    for (int ks = 0; ks < 4; ++ks)
      vfrag[ks] = *(const half8*)(vbase + j0 + (ks*4 + lq)*8);

    // ---- phase 1: SAD distances, 4 i x 4 j per thread, k8s[cur] ----
    unsigned sacc[4][4] = {};
#pragma unroll
    for (int c4 = 0; c4 < 4; ++c4) {
      uint4 kk[4];
#pragma unroll
      for (int jj = 0; jj < 4; ++jj)
        kk[jj] = *(const uint4*)&k8s[cur][(jt5*4 + jj)*64 + ((c4 ^ kswz) << 4)];
#pragma unroll
      for (int n = 0; n < 4; ++n)
#pragma unroll
        for (int jj = 0; jj < 4; ++jj) {
          sacc[n][jj] = sadU8(qr[n][c4*4+0], kk[jj].x, sacc[n][jj]);
          sacc[n][jj] = sadU8(qr[n][c4*4+1], kk[jj].y, sacc[n][jj]);
          sacc[n][jj] = sadU8(qr[n][c4*4+2], kk[jj].z, sacc[n][jj]);
          sacc[n][jj] = sadU8(qr[n][c4*4+3], kk[jj].w, sacc[n][jj]);
        }
    }
    // kern = exp(-dist/16), dist = sad/16  ->  exp2(-sad * log2(e)/256)
#pragma unroll
    for (int n = 0; n < 4; ++n) {
      half4v sv;
#pragma unroll
      for (int jj = 0; jj < 4; ++jj) {
        float sf = exp2f(-0.0056355275f * (float)sacc[n][jj]);
        rs[n] += sf;
        sv[jj] = (f16)sf;
      }
      // A-frag: cols jt5*4+jj -> slice ksj5, quarter lqp, elems e0..e0+3;
      // row iL8+n*8 -> mt = n>>1, row-in-16 = iL8 + (n&1)*8
      int row = iL8 + n*8;
      int slot = ((row >> 4)*4 + ksj5)*64 + lqp*16 + (row & 15);
      *(half4v*)&sfrag[cur][slot*8 + e0] = sv;
    }
    __syncthreads();   // sfrag[cur] ready; k8s[cur^1] landed (vmcnt drain)

    // ---- phase 2: PV via MFMA, wave tile 32i x 16d, B from regs ----
#pragma unroll
    for (int ks = 0; ks < 4; ++ks) {
      half8 a0 = *(const half8*)&sfrag[cur][((0*4 + ks)*64 + lane)*8];
      half8 a1 = *(const half8*)&sfrag[cur][((1*4 + ks)*64 + lane)*8];
      pacc[0] = __builtin_amdgcn_mfma_f32_16x16x32_f16(a0, vfrag[ks], pacc[0], 0, 0, 0);
      pacc[1] = __builtin_amdgcn_mfma_f32_16x16x32_f16(a1, vfrag[ks], pacc[1], 0, 0, 0);
    }
  }

  // rowsum reduction across the 32 j-slices
#pragma unroll
  for (int n = 0; n < 4; ++n) rspart[jt5*32 + iL8 + n*8] = rs[n];
  __syncthreads();
  if (tid < 32) {
    float s = 0.f;
#pragma unroll
    for (int t = 0; t < 32; ++t) s += rspart[t*32 + tid];
    rowsum[tid] = s + 1e-6f;
  }
  __syncthreads();

  // epilogue: normalize + depthwise conv + store y16 [b,s,h*64+d]
  const int b = bh >> 4, h = bh & 15;
  {
    int d = wave*16 + li;
    int c = h*64 + d;
    float w0 = dwcw[c*3+0], w1 = dwcw[c*3+1], w2 = dwcw[c*3+2], cb = dwcb[c];
    const f16* vrow = vTg + ((size_t)(bh*HD) + d)*SEQ;
#pragma unroll
    for (int mt = 0; mt < 2; ++mt) {
      int s0 = i0 + mt*16 + lq*4;                  // first of 4 consecutive rows
      float vv[6];
#pragma unroll
      for (int e = 0; e < 6; ++e) {
        int s = s0 - 1 + e;
        vv[e] = (s >= 0 && s < SEQ) ? (float)vrow[s] : 0.f;
      }
#pragma unroll
      for (int r = 0; r < 4; ++r) {
        int ii = mt*16 + lq*4 + r;
        float val = pacc[mt][r] / rowsum[ii];
        val += w0*vv[r] + w1*vv[r+1] + w2*vv[r+2] + cb;
        int s = i0 + ii;
        y16[((size_t)(b*SEQ + s))*DIMC + c] = (f16)val;
      }
    }
  }
}

extern "C" void kernel_launch(void* const* d_in, const int* in_sizes, int n_in,
                              void* d_out, int out_size, void* d_ws, size_t ws_size,
                              hipStream_t stream) {
  const float* x      = (const float*)d_in[0];
  const float* qkv_w  = (const float*)d_in[1];
  const float* qkv_b  = (const float*)d_in[2];
  const float* proj_w = (const float*)d_in[3];
  const float* proj_b = (const float*)d_in[4];
  const float* dwc_w  = (const float*)d_in[5];
  const float* dwc_b  = (const float*)d_in[6];
  float* out = (float*)d_out;

  char* ws = (char*)d_ws;
  f16* x16  = (f16*)(ws);                         //  4 MB
  f16* wq16 = (f16*)(ws + (4ll<<20));             //  6 MB
  f16* wp16 = (f16*)(ws + (10ll<<20));            //  2 MB
  unsigned char* q8 = (unsigned char*)(ws + (12ll<<20));  // 2 MB
  unsigned char* k8 = (unsigned char*)(ws + (14ll<<20));  // 2 MB
  f16* vT   = (f16*)(ws + (16ll<<20));            //  4 MB
  f16* y16  = (f16*)(ws + (20ll<<20));            //  4 MB (total 24 MB)

  cvt_kernel<<<1536, 256, 0, stream>>>(x, qkv_w, proj_w, x16, wq16, wp16);
  // gemm0: 128x128 tile, BK=128 (8 K-iters) — grid 24x16 = 384 blocks (proven)
  gemm_kernel<128,128,128,2,0><<<dim3(24, 16), 256, 0, stream>>>(x16, wq16, qkv_b, q8, k8, vT, nullptr, DIMC);
  // attn: 1024 blocks (32 bh x 32 i-blocks of 32 rows) = 4 blocks/CU
  attn_kernel<<<dim3(16, 64), 256, 0, stream>>>(q8, k8, vT, dwc_w, dwc_b, y16);
  // gemm1: 64x64 tile, BK=128 — grid 16x32 = 512 blocks (proven)
  gemm_kernel<64,64,128,4,1><<<dim3(16, 32), 256, 0, stream>>>(y16, wp16, proj_b, nullptr, nullptr, nullptr, out, DIMC);
}

// Round 9
// 152.436 us; speedup vs baseline: 1.0417x; 1.0417x over previous
//
#include <hip/hip_runtime.h>

#define DIMC 1024
#define HEADS 16
#define HD 64
#define BATCH 2
#define SEQ 1024
#define NQKV 3072

typedef _Float16 f16;
typedef _Float16 half8 __attribute__((ext_vector_type(8)));
typedef _Float16 half4v __attribute__((ext_vector_type(4)));
typedef float floatx4 __attribute__((ext_vector_type(4)));

__device__ __forceinline__ void gld16(const void* g, void* l) {
  __builtin_amdgcn_global_load_lds((const __attribute__((address_space(1))) void*)g,
                                   (__attribute__((address_space(3))) void*)l, 16, 0, 0);
}

__device__ __forceinline__ unsigned sadU8(unsigned a, unsigned b, unsigned c) {
#if __has_builtin(__builtin_amdgcn_sad_u8)
  return __builtin_amdgcn_sad_u8(a, b, c);
#else
  unsigned d;
  asm("v_sad_u8 %0, %1, %2, %3" : "=v"(d) : "v"(a), "v"(b), "v"(c));
  return d;
#endif
}

// ---------------- f32 -> f16 casts (x, qkv_w, proj_w), 4 float4/thread ----------------
__global__ __launch_bounds__(256) void cvt_kernel(
    const float* __restrict__ x, const float* __restrict__ wq, const float* __restrict__ wp,
    f16* __restrict__ x16, f16* __restrict__ wq16, f16* __restrict__ wp16)
{
  int bid = blockIdx.x;
  const float* src; f16* dst; int base;
  if (bid < 512)        { src = x;  dst = x16;  base = bid; }
  else if (bid < 1280)  { src = wq; dst = wq16; base = bid - 512; }
  else                  { src = wp; dst = wp16; base = bid - 1280; }
  long long i0 = (long long)base*1024 + threadIdx.x;
#pragma unroll
  for (int k2 = 0; k2 < 4; ++k2) {
    long long i = i0 + k2*256;   // float4 index, coalesced
    float4 v = ((const float4*)src)[i];
    half4v h; h[0]=(f16)v.x; h[1]=(f16)v.y; h[2]=(f16)v.z; h[3]=(f16)v.w;
    *(half4v*)(dst + i*4) = h;
  }
}

// ---------------- TM x TN f16 MFMA GEMM (BK-deep K-tiles), C = A * Bw^T + bias ----
// MODE 0: QKV -> q8/k8 (u8 quant, [b,h,s,d]) and vT (f16, [b,h,d,s])
// MODE 1: proj -> f32 out [t, f]
// Proven configs: gemm0 128x128 BK128 MW2, gemm1 64x64 BK128 MW4.
template<int TM, int TN, int BK, int MW, int MODE>
__global__ __launch_bounds__(256, MW) void gemm_kernel(
    const f16* __restrict__ A, const f16* __restrict__ Bw, const float* __restrict__ bias,
    unsigned char* __restrict__ q8, unsigned char* __restrict__ k8, f16* __restrict__ vT,
    float* __restrict__ outp, int K)
{
  constexpr int MT = TM / 32;   // m-subtiles per wave
  constexpr int NT = TN / 32;   // n-subtiles per wave
  constexpr int G  = BK / 8;    // 16B groups per LDS row
  __shared__ f16 As[TM*BK];
  __shared__ f16 Bs[TN*BK];
  const int tid = threadIdx.x;
  const int wave = tid >> 6, lane = tid & 63;
  const int lq = lane >> 4, li = lane & 15;
  const int m0 = blockIdx.y * TM, n0 = blockIdx.x * TN;
  const int wm = (wave & 1) * (TM/2), wn = (wave >> 1) * (TN/2);
  floatx4 acc[MT][NT] = {};

  const int kIters = K / BK;
  for (int kt = 0; kt < kIters; ++kt) {
    __syncthreads();
#pragma unroll
    for (int r = 0; r < TM*BK/2048; ++r) {
      int slot = r*256 + tid;
      int row = slot / G, c = slot % G, g = c ^ (row & (G-1));
      gld16(A + (size_t)(m0+row)*K + kt*BK + g*8, As + slot*8);
    }
#pragma unroll
    for (int r = 0; r < TN*BK/2048; ++r) {
      int slot = r*256 + tid;
      int row = slot / G, c = slot % G, g = c ^ (row & (G-1));
      gld16(Bw + (size_t)(n0+row)*K + kt*BK + g*8, Bs + slot*8);
    }
    __syncthreads();
#pragma unroll
    for (int ks = 0; ks < BK/32; ++ks) {
      half8 af[MT], bf[NT];
      int kc = ks*4 + lq;
#pragma unroll
      for (int t = 0; t < MT; ++t) {
        int am = wm + t*16 + li;
        af[t] = *(const half8*)&As[am*BK + (kc ^ (am & (G-1)))*8];
      }
#pragma unroll
      for (int t = 0; t < NT; ++t) {
        int bn = wn + t*16 + li;
        bf[t] = *(const half8*)&Bs[bn*BK + (kc ^ (bn & (G-1)))*8];
      }
#pragma unroll
      for (int mt = 0; mt < MT; ++mt)
#pragma unroll
        for (int nt = 0; nt < NT; ++nt)
          acc[mt][nt] = __builtin_amdgcn_mfma_f32_16x16x32_f16(af[mt], bf[nt], acc[mt][nt], 0, 0, 0);
    }
  }

#pragma unroll
  for (int mt = 0; mt < MT; ++mt) {
#pragma unroll
    for (int nt = 0; nt < NT; ++nt) {
      int f = n0 + wn + nt*16 + li;                 // output feature (col, from B)
      float bb = bias[f];
      if (MODE == 0) {
        int which = f >> 10, cc = f & 1023, h = cc >> 6, d = cc & 63;
        int t0 = m0 + wm + mt*16 + lq*4;            // token (row, from A), 4 consecutive
        int b = t0 >> 10, s0 = t0 & 1023;
        if (which == 2) {
          half4v hv;
#pragma unroll
          for (int r = 0; r < 4; ++r) hv[r] = (f16)(acc[mt][nt][r] + bb);
          *(half4v*)&vT[((size_t)((b*HEADS + h)*HD + d))*SEQ + s0] = hv;
        } else {
          unsigned char* dst = (which == 0) ? q8 : k8;
#pragma unroll
          for (int r = 0; r < 4; ++r) {
            float v = acc[mt][nt][r] + bb;
            int u = (int)floorf(v * 16.0f + 128.5f);
            u = u < 0 ? 0 : (u > 255 ? 255 : u);
            dst[((size_t)((b*HEADS + h)*SEQ + s0 + r))*HD + d] = (unsigned char)u;
          }
        }
      } else {
#pragma unroll
        for (int r = 0; r < 4; ++r) {
          int t = m0 + wm + mt*16 + lq*4 + r;
          outp[(size_t)t*DIMC + f] = acc[mt][nt][r] + bb;
        }
      }
    }
  }
}

// ---------------- Laplacian attention + depthwise conv, y16 out ----------------
// R21: sfrag ELIMINATED via j-partial PV. Insight: the 2ix8j thread's sv half8
// is ALREADY the MFMA A-frag for its wave's 32-j block (lane=(jt&3)*16+iL ->
// row=lane&15, k=(lane>>4)*8+e). Decompose PV by j: each wave accumulates a
// partial 32i x 64d over its OWN 32 j (pacc[2][4], B-frags per-dt from vT
// global/L2). No score exchange -> no sfrag (LDS instr/thread/jb 42->32), and
// the per-jb barrier only guards the k8s dbuf handoff (SAD->PV decoupled).
// Cross-wave combine once at end via 16KB red buffer (2 rounds of 16 rows).
// R20 lesson: reg budget ~120 -> MW=3 (cap ~170; R19 achieved only 28% occ at
// the 4-block cap, so the 3-block cap is ~free). Spill tripwire: WRITE_SIZE.
__global__ __launch_bounds__(256, 3) void attn_kernel(
    const unsigned char* __restrict__ q8g, const unsigned char* __restrict__ k8g,
    const f16* __restrict__ vTg, const float* __restrict__ dwcw, const float* __restrict__ dwcb,
    f16* __restrict__ y16)
{
  __shared__ unsigned char q8s[32*64];     //  2KB
  __shared__ unsigned char k8s[2][128*64]; // 16KB double-buffered, chunk-swizzled
  __shared__ float red[4][16][64];         // 16KB cross-wave PV partials
  __shared__ float rspart[32*16];          //  2KB
  __shared__ float rowsum[32];             // total ~36.6KB

  const int tid = threadIdx.x;
  const int lin = blockIdx.x + 16 * blockIdx.y;      // 0..1023
  const int bh = (lin & 7) * 4 + ((lin >> 3) & 3);   // XCD-grouped head index
  const int i0 = (lin >> 5) * 32;                    // 32 i-blocks of 32 rows
  const int lane = tid & 63, wave = tid >> 6;
  const int lq = lane >> 4, li = lane & 15;
  const int iL = tid & 15, jt = tid >> 4;       // phase-1 mapping (2i x 8j)
  const int scs = jt & 3;                       // chunk-swizzle read key

  { // stage q tile (32x64B, waves 0-1) + k8s[0] with chunk swizzle
    if (tid < 128)
      gld16(q8g + ((size_t)(bh*SEQ) + i0)*HD + tid*16, q8s + tid*16);
#pragma unroll
    for (int r = 0; r < 2; ++r) {
      int slot = r*256 + tid;
      int row = slot >> 2, c4 = slot & 3, sc4 = c4 ^ ((row >> 3) & 3);
      gld16(k8g + ((size_t)(bh*SEQ) + row)*HD + sc4*16, k8s[0] + slot*16);
    }
  }
  __syncthreads();

  // q rows {iL, iL+16} into regs (32 u32 — the size that provably stays resident)
  unsigned qr[2][16];
#pragma unroll
  for (int n = 0; n < 2; ++n)
#pragma unroll
    for (int c4 = 0; c4 < 4; ++c4) {
      uint4 t = *(const uint4*)&q8s[(iL + n*16)*64 + c4*16];
      qr[n][c4*4+0] = t.x; qr[n][c4*4+1] = t.y; qr[n][c4*4+2] = t.z; qr[n][c4*4+3] = t.w;
    }

  float rs[2] = {0.f, 0.f};
  floatx4 pacc[2][4] = {};               // [n(i-half)][dt] j-partial, this wave's 32 j
  const int jw = wave*32 + lq*8;         // B-frag j-offset within the 128-tile

  for (int jb = 0; jb < 8; ++jb) {
    const int j0 = jb * 128;
    const int cur = jb & 1;

    // stage NEXT k tile (consumed in iter jb+1; lands by this iter's barrier)
    if (jb < 7) {
#pragma unroll
      for (int r = 0; r < 2; ++r) {
        int slot = r*256 + tid;
        int row = slot >> 2, c4 = slot & 3, sc4 = c4 ^ ((row >> 3) & 3);
        gld16(k8g + ((size_t)(bh*SEQ) + j0 + 128 + row)*HD + sc4*16,
              k8s[cur ^ 1] + slot*16);
      }
    }
    // B-frags for this wave's j-block, one per d-tile (global/L2, issue early)
    half8 vfrag[4];
#pragma unroll
    for (int dt = 0; dt < 4; ++dt)
      vfrag[dt] = *(const half8*)(vTg + ((size_t)(bh*HD) + dt*16 + li)*SEQ + j0 + jw);

    // ---- SAD distances, 2 i x 8 j per thread, from k8s[cur] ----
    unsigned sacc[2][8] = {};
#pragma unroll
    for (int c4 = 0; c4 < 4; ++c4) {
      uint4 kk[8];
#pragma unroll
      for (int jj = 0; jj < 8; ++jj)
        kk[jj] = *(const uint4*)&k8s[cur][(jt*8 + jj)*64 + ((c4 ^ scs) << 4)];
#pragma unroll
      for (int n = 0; n < 2; ++n)
#pragma unroll
        for (int jj = 0; jj < 8; ++jj) {
          sacc[n][jj] = sadU8(qr[n][c4*4+0], kk[jj].x, sacc[n][jj]);
          sacc[n][jj] = sadU8(qr[n][c4*4+1], kk[jj].y, sacc[n][jj]);
          sacc[n][jj] = sadU8(qr[n][c4*4+2], kk[jj].z, sacc[n][jj]);
          sacc[n][jj] = sadU8(qr[n][c4*4+3], kk[jj].w, sacc[n][jj]);
        }
    }
    // kern = exp2(-sad * log2(e)/256); sv IS the A-frag for this wave's j-block
#pragma unroll
    for (int n = 0; n < 2; ++n) {
      half8 sv;
#pragma unroll
      for (int jj = 0; jj < 8; ++jj) {
        float sf = exp2f(-0.0056355275f * (float)sacc[n][jj]);
        rs[n] += sf;
        sv[jj] = (f16)sf;
      }
#pragma unroll
      for (int dt = 0; dt < 4; ++dt)
        pacc[n][dt] = __builtin_amdgcn_mfma_f32_16x16x32_f16(sv, vfrag[dt], pacc[n][dt], 0, 0, 0);
    }
    __syncthreads();   // k8s dbuf handoff only (sfrag is gone)
  }

  // rowsum reduction across the 16 j-slices
#pragma unroll
  for (int n = 0; n < 2; ++n) rspart[(iL + n*16)*16 + jt] = rs[n];
  __syncthreads();
  if (tid < 32) {
    float s = 0.f;
#pragma unroll
    for (int t = 0; t < 16; ++t) s += rspart[tid*16 + t];
    rowsum[tid] = s + 1e-6f;
  }
  __syncthreads();

  // epilogue: combine 4 j-partials, normalize, depthwise conv, store y16
  const int b = bh >> 4, h = bh & 15;
  const int ie = tid >> 4, d40 = (tid & 15) * 4;   // reduce mapping: (i, 4 d's)
#pragma unroll
  for (int half = 0; half < 2; ++half) {
    // write this wave's partial rows [half*16, half*16+16)
#pragma unroll
    for (int dt = 0; dt < 4; ++dt)
#pragma unroll
      for (int r = 0; r < 4; ++r)
        red[wave][lq*4 + r][dt*16 + li] = pacc[half][dt][r];
    __syncthreads();
    float4 s = make_float4(0.f, 0.f, 0.f, 0.f);
#pragma unroll
    for (int w = 0; w < 4; ++w) {
      float4 t = *(const float4*)&red[w][ie][d40];
      s.x += t.x; s.y += t.y; s.z += t.z; s.w += t.w;
    }
    int srow = i0 + half*16 + ie;
    float rsum = rowsum[half*16 + ie];
    float sa[4] = {s.x, s.y, s.z, s.w};
    half4v outv;
#pragma unroll
    for (int c = 0; c < 4; ++c) {
      int d = d40 + c;
      int ch = h*64 + d;
      const f16* vrow = vTg + ((size_t)(bh*HD) + d)*SEQ;
      float vm1 = (srow - 1 >= 0) ? (float)vrow[srow - 1] : 0.f;
      float v0  = (float)vrow[srow];
      float vp1 = (srow + 1 < SEQ) ? (float)vrow[srow + 1] : 0.f;
      float val = sa[c] / rsum
                + dwcw[ch*3+0]*vm1 + dwcw[ch*3+1]*v0 + dwcw[ch*3+2]*vp1 + dwcb[ch];
      outv[c] = (f16)val;
    }
    *(half4v*)&y16[((size_t)(b*SEQ + srow))*DIMC + h*64 + d40] = outv;
    if (half == 0) __syncthreads();   // red reuse guard
  }
}

extern "C" void kernel_launch(void* const* d_in, const int* in_sizes, int n_in,
                              void* d_out, int out_size, void* d_ws, size_t ws_size,
                              hipStream_t stream) {
  const float* x      = (const float*)d_in[0];
  const float* qkv_w  = (const float*)d_in[1];
  const float* qkv_b  = (const float*)d_in[2];
  const float* proj_w = (const float*)d_in[3];
  const float* proj_b = (const float*)d_in[4];
  const float* dwc_w  = (const float*)d_in[5];
  const float* dwc_b  = (const float*)d_in[6];
  float* out = (float*)d_out;

  char* ws = (char*)d_ws;
  f16* x16  = (f16*)(ws);                         //  4 MB
  f16* wq16 = (f16*)(ws + (4ll<<20));             //  6 MB
  f16* wp16 = (f16*)(ws + (10ll<<20));            //  2 MB
  unsigned char* q8 = (unsigned char*)(ws + (12ll<<20));  // 2 MB
  unsigned char* k8 = (unsigned char*)(ws + (14ll<<20));  // 2 MB
  f16* vT   = (f16*)(ws + (16ll<<20));            //  4 MB
  f16* y16  = (f16*)(ws + (20ll<<20));            //  4 MB (total 24 MB)

  cvt_kernel<<<1536, 256, 0, stream>>>(x, qkv_w, proj_w, x16, wq16, wp16);
  // gemm0: 128x128 tile, BK=128 (8 K-iters) — grid 24x16 = 384 blocks (proven)
  gemm_kernel<128,128,128,2,0><<<dim3(24, 16), 256, 0, stream>>>(x16, wq16, qkv_b, q8, k8, vT, nullptr, DIMC);
  // attn: 1024 blocks (32 bh x 32 i-blocks of 32 rows)
  attn_kernel<<<dim3(16, 64), 256, 0, stream>>>(q8, k8, vT, dwc_w, dwc_b, y16);
  // gemm1: 64x64 tile, BK=128 — grid 16x32 = 512 blocks (proven)
  gemm_kernel<64,64,128,4,1><<<dim3(16, 32), 256, 0, stream>>>(y16, wp16, proj_b, nullptr, nullptr, nullptr, out, DIMC);
}

// Round 10
// 149.451 us; speedup vs baseline: 1.0625x; 1.0200x over previous
//
#include <hip/hip_runtime.h>

#define DIMC 1024
#define HEADS 16
#define HD 64
#define BATCH 2
#define SEQ 1024
#define NQKV 3072

typedef _Float16 f16;
typedef _Float16 half8 __attribute__((ext_vector_type(8)));
typedef _Float16 half4v __attribute__((ext_vector_type(4)));
typedef float floatx4 __attribute__((ext_vector_type(4)));

__device__ __forceinline__ void gld16(const void* g, void* l) {
  __builtin_amdgcn_global_load_lds((const __attribute__((address_space(1))) void*)g,
                                   (__attribute__((address_space(3))) void*)l, 16, 0, 0);
}

__device__ __forceinline__ unsigned sadU8(unsigned a, unsigned b, unsigned c) {
#if __has_builtin(__builtin_amdgcn_sad_u8)
  return __builtin_amdgcn_sad_u8(a, b, c);
#else
  unsigned d;
  asm("v_sad_u8 %0, %1, %2, %3" : "=v"(d) : "v"(a), "v"(b), "v"(c));
  return d;
#endif
}

// ---------------- f32 -> f16 casts (x, qkv_w, proj_w), 4 float4/thread ----------------
__global__ __launch_bounds__(256) void cvt_kernel(
    const float* __restrict__ x, const float* __restrict__ wq, const float* __restrict__ wp,
    f16* __restrict__ x16, f16* __restrict__ wq16, f16* __restrict__ wp16)
{
  int bid = blockIdx.x;
  const float* src; f16* dst; int base;
  if (bid < 512)        { src = x;  dst = x16;  base = bid; }
  else if (bid < 1280)  { src = wq; dst = wq16; base = bid - 512; }
  else                  { src = wp; dst = wp16; base = bid - 1280; }
  long long i0 = (long long)base*1024 + threadIdx.x;
#pragma unroll
  for (int k2 = 0; k2 < 4; ++k2) {
    long long i = i0 + k2*256;   // float4 index, coalesced
    float4 v = ((const float4*)src)[i];
    half4v h; h[0]=(f16)v.x; h[1]=(f16)v.y; h[2]=(f16)v.z; h[3]=(f16)v.w;
    *(half4v*)(dst + i*4) = h;
  }
}

// ---------------- TM x TN f16 MFMA GEMM (BK-deep K-tiles), C = A * Bw^T + bias ----
// MODE 0: QKV -> q8/k8 (u8 quant, [b,h,s,d]) and vT (f16, [b,h,d,s])
// MODE 1: proj -> f32 out [t, f]
// Proven configs: gemm0 128x128 BK128 MW2, gemm1 64x64 BK128 MW4.
template<int TM, int TN, int BK, int MW, int MODE>
__global__ __launch_bounds__(256, MW) void gemm_kernel(
    const f16* __restrict__ A, const f16* __restrict__ Bw, const float* __restrict__ bias,
    unsigned char* __restrict__ q8, unsigned char* __restrict__ k8, f16* __restrict__ vT,
    float* __restrict__ outp, int K)
{
  constexpr int MT = TM / 32;   // m-subtiles per wave
  constexpr int NT = TN / 32;   // n-subtiles per wave
  constexpr int G  = BK / 8;    // 16B groups per LDS row
  __shared__ f16 As[TM*BK];
  __shared__ f16 Bs[TN*BK];
  const int tid = threadIdx.x;
  const int wave = tid >> 6, lane = tid & 63;
  const int lq = lane >> 4, li = lane & 15;
  const int m0 = blockIdx.y * TM, n0 = blockIdx.x * TN;
  const int wm = (wave & 1) * (TM/2), wn = (wave >> 1) * (TN/2);
  floatx4 acc[MT][NT] = {};

  const int kIters = K / BK;
  for (int kt = 0; kt < kIters; ++kt) {
    __syncthreads();
#pragma unroll
    for (int r = 0; r < TM*BK/2048; ++r) {
      int slot = r*256 + tid;
      int row = slot / G, c = slot % G, g = c ^ (row & (G-1));
      gld16(A + (size_t)(m0+row)*K + kt*BK + g*8, As + slot*8);
    }
#pragma unroll
    for (int r = 0; r < TN*BK/2048; ++r) {
      int slot = r*256 + tid;
      int row = slot / G, c = slot % G, g = c ^ (row & (G-1));
      gld16(Bw + (size_t)(n0+row)*K + kt*BK + g*8, Bs + slot*8);
    }
    __syncthreads();
#pragma unroll
    for (int ks = 0; ks < BK/32; ++ks) {
      half8 af[MT], bf[NT];
      int kc = ks*4 + lq;
#pragma unroll
      for (int t = 0; t < MT; ++t) {
        int am = wm + t*16 + li;
        af[t] = *(const half8*)&As[am*BK + (kc ^ (am & (G-1)))*8];
      }
#pragma unroll
      for (int t = 0; t < NT; ++t) {
        int bn = wn + t*16 + li;
        bf[t] = *(const half8*)&Bs[bn*BK + (kc ^ (bn & (G-1)))*8];
      }
#pragma unroll
      for (int mt = 0; mt < MT; ++mt)
#pragma unroll
        for (int nt = 0; nt < NT; ++nt)
          acc[mt][nt] = __builtin_amdgcn_mfma_f32_16x16x32_f16(af[mt], bf[nt], acc[mt][nt], 0, 0, 0);
    }
  }

#pragma unroll
  for (int mt = 0; mt < MT; ++mt) {
#pragma unroll
    for (int nt = 0; nt < NT; ++nt) {
      int f = n0 + wn + nt*16 + li;                 // output feature (col, from B)
      float bb = bias[f];
      if (MODE == 0) {
        int which = f >> 10, cc = f & 1023, h = cc >> 6, d = cc & 63;
        int t0 = m0 + wm + mt*16 + lq*4;            // token (row, from A), 4 consecutive
        int b = t0 >> 10, s0 = t0 & 1023;
        if (which == 2) {
          half4v hv;
#pragma unroll
          for (int r = 0; r < 4; ++r) hv[r] = (f16)(acc[mt][nt][r] + bb);
          *(half4v*)&vT[((size_t)((b*HEADS + h)*HD + d))*SEQ + s0] = hv;
        } else {
          unsigned char* dst = (which == 0) ? q8 : k8;
#pragma unroll
          for (int r = 0; r < 4; ++r) {
            float v = acc[mt][nt][r] + bb;
            int u = (int)floorf(v * 16.0f + 128.5f);
            u = u < 0 ? 0 : (u > 255 ? 255 : u);
            dst[((size_t)((b*HEADS + h)*SEQ + s0 + r))*HD + d] = (unsigned char)u;
          }
        }
      } else {
#pragma unroll
        for (int r = 0; r < 4; ++r) {
          int t = m0 + wm + mt*16 + lq*4 + r;
          outp[(size_t)t*DIMC + f] = acc[mt][nt][r] + bb;
        }
      }
    }
  }
}

// ---------------- Laplacian attention + depthwise conv, y16 out ----------------
// R22 = R19 skeleton (proven best: attn 44.5us, total 146.5) + two minimal
// latency edits. R21's sfrag-free rewrite was clean (no spill) but slower
// (48.6us): per-loop scatter vfrag vmcnt waits entered the inner path ->
// reverted. Remaining stalls are dependency-latency (VALU 54%, LDS ~40%,
// neither saturated):
// (1) kk c4-group double-buffer (kkA/kkB, +32 VGPR at MW=3 cap ~170): group
//     c4+1's 8 ds_read_b128 issue before group c4's SADs -> lgkmcnt chain
//     covered by ~64 SAD instrs. All indices compile-time (rule #20 safe).
// (2) s_setprio(1) around PV MFMA cluster (T5; m191 regime: independent
//     blocks at different phases, +4-7% attn).
__global__ __launch_bounds__(256, 3) void attn_kernel(
    const unsigned char* __restrict__ q8g, const unsigned char* __restrict__ k8g,
    const f16* __restrict__ vTg, const float* __restrict__ dwcw, const float* __restrict__ dwcb,
    f16* __restrict__ y16)
{
  __shared__ unsigned char q8s[32*64];     //  2KB
  __shared__ unsigned char k8s[2][128*64]; // 16KB double-buffered, chunk-swizzled
  __shared__ f16 sfrag[2][8*64*8];         // 16KB double-buffered A-frag scores
  __shared__ float rspart[32*16];          //  2KB
  __shared__ float rowsum[32];             // total ~36.4KB

  const int tid = threadIdx.x;
  const int lin = blockIdx.x + 16 * blockIdx.y;      // 0..1023
  const int bh = (lin & 7) * 4 + ((lin >> 3) & 3);   // XCD-grouped head index
  const int i0 = (lin >> 5) * 32;                    // 32 i-blocks of 32 rows
  const int lane = tid & 63, wave = tid >> 6;
  const int lq = lane >> 4, li = lane & 15;
  const int iL = tid & 15, jt = tid >> 4;       // phase-1 mapping
  const int ksj = jt >> 2, qj = jt & 3;
  const int scs = jt & 3;                       // chunk-swizzle read key

  { // stage q tile (32x64B, waves 0-1) + k8s[0] with chunk swizzle
    if (tid < 128)
      gld16(q8g + ((size_t)(bh*SEQ) + i0)*HD + tid*16, q8s + tid*16);
#pragma unroll
    for (int r = 0; r < 2; ++r) {
      int slot = r*256 + tid;
      int row = slot >> 2, c4 = slot & 3, sc4 = c4 ^ ((row >> 3) & 3);
      gld16(k8g + ((size_t)(bh*SEQ) + row)*HD + sc4*16, k8s[0] + slot*16);
    }
  }
  __syncthreads();

  // q rows {iL, iL+16} into regs (32 u32)
  unsigned qr[2][16];
#pragma unroll
  for (int n = 0; n < 2; ++n)
#pragma unroll
    for (int c4 = 0; c4 < 4; ++c4) {
      uint4 t = *(const uint4*)&q8s[(iL + n*16)*64 + c4*16];
      qr[n][c4*4+0] = t.x; qr[n][c4*4+1] = t.y; qr[n][c4*4+2] = t.z; qr[n][c4*4+3] = t.w;
    }

  float rs[2] = {0.f, 0.f};
  floatx4 pacc[2] = {};                  // this wave owns d-strip wave*16..+15
  const f16* vbase = vTg + ((size_t)(bh*HD) + wave*16 + li)*SEQ;

  for (int jb = 0; jb < 8; ++jb) {
    const int j0 = jb * 128;
    const int cur = jb & 1;

    // stage NEXT k tile (consumed in iter jb+1; lands by this iter's barrier)
    if (jb < 7) {
#pragma unroll
      for (int r = 0; r < 2; ++r) {
        int slot = r*256 + tid;
        int row = slot >> 2, c4 = slot & 3, sc4 = c4 ^ ((row >> 3) & 3);
        gld16(k8g + ((size_t)(bh*SEQ) + j0 + 128 + row)*HD + sc4*16,
              k8s[cur ^ 1] + slot*16);
      }
    }
    // issue this iter's V B-frags (global->reg, waited at MFMA use)
    half8 vfrag[4];
#pragma unroll
    for (int ks = 0; ks < 4; ++ks)
      vfrag[ks] = *(const half8*)(vbase + j0 + (ks*4 + lq)*8);

    // ---- phase 1: SAD distances from k8s[cur], c4-group double-buffered ----
    unsigned sacc[2][8] = {};
    uint4 kkA[8], kkB[8];
#pragma unroll
    for (int jj = 0; jj < 8; ++jj)
      kkA[jj] = *(const uint4*)&k8s[cur][(jt*8 + jj)*64 + ((0 ^ scs) << 4)];
#pragma unroll
    for (int c4 = 0; c4 < 4; ++c4) {
      const uint4* kkc = (c4 & 1) ? kkB : kkA;
      uint4*       kkn = (c4 & 1) ? kkA : kkB;
      if (c4 < 3) {
#pragma unroll
        for (int jj = 0; jj < 8; ++jj)
          kkn[jj] = *(const uint4*)&k8s[cur][(jt*8 + jj)*64 + (((c4+1) ^ scs) << 4)];
      }
#pragma unroll
      for (int n = 0; n < 2; ++n)
#pragma unroll
        for (int jj = 0; jj < 8; ++jj) {
          sacc[n][jj] = sadU8(qr[n][c4*4+0], kkc[jj].x, sacc[n][jj]);
          sacc[n][jj] = sadU8(qr[n][c4*4+1], kkc[jj].y, sacc[n][jj]);
          sacc[n][jj] = sadU8(qr[n][c4*4+2], kkc[jj].z, sacc[n][jj]);
          sacc[n][jj] = sadU8(qr[n][c4*4+3], kkc[jj].w, sacc[n][jj]);
        }
    }
    // kern = exp(-dist/16), dist = sad/16  ->  exp2(-sad * log2(e)/256)
#pragma unroll
    for (int n = 0; n < 2; ++n) {
      half8 sv;
#pragma unroll
      for (int jj = 0; jj < 8; ++jj) {
        float sf = exp2f(-0.0056355275f * (float)sacc[n][jj]);
        rs[n] += sf;
        sv[jj] = (f16)sf;
      }
      *(half8*)&sfrag[cur][((n*4 + ksj)*64 + qj*16 + iL)*8] = sv;
    }
    __syncthreads();   // sfrag[cur] ready; k8s[cur^1] landed (vmcnt drain)

    // ---- phase 2: PV via MFMA, wave tile 32i x 16d, B from regs ----
    __builtin_amdgcn_s_setprio(1);
#pragma unroll
    for (int ks = 0; ks < 4; ++ks) {
      half8 a0 = *(const half8*)&sfrag[cur][((0*4 + ks)*64 + lane)*8];
      half8 a1 = *(const half8*)&sfrag[cur][((1*4 + ks)*64 + lane)*8];
      pacc[0] = __builtin_amdgcn_mfma_f32_16x16x32_f16(a0, vfrag[ks], pacc[0], 0, 0, 0);
      pacc[1] = __builtin_amdgcn_mfma_f32_16x16x32_f16(a1, vfrag[ks], pacc[1], 0, 0, 0);
    }
    __builtin_amdgcn_s_setprio(0);
  }

  // rowsum reduction across the 16 j-slices
#pragma unroll
  for (int n = 0; n < 2; ++n) rspart[(iL + n*16)*16 + jt] = rs[n];
  __syncthreads();
  if (tid < 32) {
    float s = 0.f;
#pragma unroll
    for (int t = 0; t < 16; ++t) s += rspart[tid*16 + t];
    rowsum[tid] = s + 1e-6f;
  }
  __syncthreads();

  // epilogue: normalize + depthwise conv + store y16 [b,s,h*64+d]
  const int b = bh >> 4, h = bh & 15;
  {
    int d = wave*16 + li;
    int c = h*64 + d;
    float w0 = dwcw[c*3+0], w1 = dwcw[c*3+1], w2 = dwcw[c*3+2], cb = dwcb[c];
    const f16* vrow = vTg + ((size_t)(bh*HD) + d)*SEQ;
#pragma unroll
    for (int mt = 0; mt < 2; ++mt) {
      int s0 = i0 + mt*16 + lq*4;                  // first of 4 consecutive rows
      float vv[6];
#pragma unroll
      for (int e = 0; e < 6; ++e) {
        int s = s0 - 1 + e;
        vv[e] = (s >= 0 && s < SEQ) ? (float)vrow[s] : 0.f;
      }
#pragma unroll
      for (int r = 0; r < 4; ++r) {
        int ii = mt*16 + lq*4 + r;
        float val = pacc[mt][r] / rowsum[ii];
        val += w0*vv[r] + w1*vv[r+1] + w2*vv[r+2] + cb;
        int s = i0 + ii;
        y16[((size_t)(b*SEQ + s))*DIMC + c] = (f16)val;
      }
    }
  }
}

extern "C" void kernel_launch(void* const* d_in, const int* in_sizes, int n_in,
                              void* d_out, int out_size, void* d_ws, size_t ws_size,
                              hipStream_t stream) {
  const float* x      = (const float*)d_in[0];
  const float* qkv_w  = (const float*)d_in[1];
  const float* qkv_b  = (const float*)d_in[2];
  const float* proj_w = (const float*)d_in[3];
  const float* proj_b = (const float*)d_in[4];
  const float* dwc_w  = (const float*)d_in[5];
  const float* dwc_b  = (const float*)d_in[6];
  float* out = (float*)d_out;

  char* ws = (char*)d_ws;
  f16* x16  = (f16*)(ws);                         //  4 MB
  f16* wq16 = (f16*)(ws + (4ll<<20));             //  6 MB
  f16* wp16 = (f16*)(ws + (10ll<<20));            //  2 MB
  unsigned char* q8 = (unsigned char*)(ws + (12ll<<20));  // 2 MB
  unsigned char* k8 = (unsigned char*)(ws + (14ll<<20));  // 2 MB
  f16* vT   = (f16*)(ws + (16ll<<20));            //  4 MB
  f16* y16  = (f16*)(ws + (20ll<<20));            //  4 MB (total 24 MB)

  cvt_kernel<<<1536, 256, 0, stream>>>(x, qkv_w, proj_w, x16, wq16, wp16);
  // gemm0: 128x128 tile, BK=128 (8 K-iters) — grid 24x16 = 384 blocks (proven)
  gemm_kernel<128,128,128,2,0><<<dim3(24, 16), 256, 0, stream>>>(x16, wq16, qkv_b, q8, k8, vT, nullptr, DIMC);
  // attn: 1024 blocks (32 bh x 32 i-blocks of 32 rows)
  attn_kernel<<<dim3(16, 64), 256, 0, stream>>>(q8, k8, vT, dwc_w, dwc_b, y16);
  // gemm1: 64x64 tile, BK=128 — grid 16x32 = 512 blocks (proven)
  gemm_kernel<64,64,128,4,1><<<dim3(16, 32), 256, 0, stream>>>(y16, wp16, proj_b, nullptr, nullptr, nullptr, out, DIMC);
}

// Round 11
// 147.098 us; speedup vs baseline: 1.0795x; 1.0160x over previous
//
#include <hip/hip_runtime.h>

#define DIMC 1024
#define HEADS 16
#define HD 64
#define BATCH 2
#define SEQ 1024
#define NQKV 3072

typedef _Float16 f16;
typedef _Float16 half8 __attribute__((ext_vector_type(8)));
typedef _Float16 half4v __attribute__((ext_vector_type(4)));
typedef float floatx4 __attribute__((ext_vector_type(4)));

__device__ __forceinline__ void gld16(const void* g, void* l) {
  __builtin_amdgcn_global_load_lds((const __attribute__((address_space(1))) void*)g,
                                   (__attribute__((address_space(3))) void*)l, 16, 0, 0);
}

__device__ __forceinline__ unsigned sadU8(unsigned a, unsigned b, unsigned c) {
#if __has_builtin(__builtin_amdgcn_sad_u8)
  return __builtin_amdgcn_sad_u8(a, b, c);
#else
  unsigned d;
  asm("v_sad_u8 %0, %1, %2, %3" : "=v"(d) : "v"(a), "v"(b), "v"(c));
  return d;
#endif
}

// ---------------- f32 -> f16 casts (x, qkv_w, proj_w), 4 float4/thread ----------------
__global__ __launch_bounds__(256) void cvt_kernel(
    const float* __restrict__ x, const float* __restrict__ wq, const float* __restrict__ wp,
    f16* __restrict__ x16, f16* __restrict__ wq16, f16* __restrict__ wp16)
{
  int bid = blockIdx.x;
  const float* src; f16* dst; int base;
  if (bid < 512)        { src = x;  dst = x16;  base = bid; }
  else if (bid < 1280)  { src = wq; dst = wq16; base = bid - 512; }
  else                  { src = wp; dst = wp16; base = bid - 1280; }
  long long i0 = (long long)base*1024 + threadIdx.x;
#pragma unroll
  for (int k2 = 0; k2 < 4; ++k2) {
    long long i = i0 + k2*256;   // float4 index, coalesced
    float4 v = ((const float4*)src)[i];
    half4v h; h[0]=(f16)v.x; h[1]=(f16)v.y; h[2]=(f16)v.z; h[3]=(f16)v.w;
    *(half4v*)(dst + i*4) = h;
  }
}

// ---------------- TM x TN f16 MFMA GEMM (BK-deep K-tiles), C = A * Bw^T + bias ----
// MODE 0: QKV -> q8/k8 (u8 quant, [b,h,s,d]) and vT (f16, [b,h,d,s])
// MODE 1: proj -> f32 out [t, f]
// R23: gemm1 64x64 BK 128->256 (kIters 8->4). Evidence: gemm0 and gemm1 both
// sit just under the top-5 cutoff (~44us each; total minus attn/cvt ~90us) ->
// gemm1 = 4.3 GFLOP / 44us = ~98 TF, the least efficient dispatch. 64x64 tile
// has half gemm0's MFMA:byte ratio and pays 8 barrier+vmcnt(0) drains at 2
// blocks/CU. BK=256 halves barriers, doubles MFMA per barrier interval, LDS
// 64KB = exactly the 2/CU the 512-block grid provides (residency unchanged —
// NOT the R14 trap). Single-variable change on the proven template.
template<int TM, int TN, int BK, int MW, int MODE>
__global__ __launch_bounds__(256, MW) void gemm_kernel(
    const f16* __restrict__ A, const f16* __restrict__ Bw, const float* __restrict__ bias,
    unsigned char* __restrict__ q8, unsigned char* __restrict__ k8, f16* __restrict__ vT,
    float* __restrict__ outp, int K)
{
  constexpr int MT = TM / 32;   // m-subtiles per wave
  constexpr int NT = TN / 32;   // n-subtiles per wave
  constexpr int G  = BK / 8;    // 16B groups per LDS row
  __shared__ f16 As[TM*BK];
  __shared__ f16 Bs[TN*BK];
  const int tid = threadIdx.x;
  const int wave = tid >> 6, lane = tid & 63;
  const int lq = lane >> 4, li = lane & 15;
  const int m0 = blockIdx.y * TM, n0 = blockIdx.x * TN;
  const int wm = (wave & 1) * (TM/2), wn = (wave >> 1) * (TN/2);
  floatx4 acc[MT][NT] = {};

  const int kIters = K / BK;
  for (int kt = 0; kt < kIters; ++kt) {
    __syncthreads();
#pragma unroll
    for (int r = 0; r < TM*BK/2048; ++r) {
      int slot = r*256 + tid;
      int row = slot / G, c = slot % G, g = c ^ (row & (G-1));
      gld16(A + (size_t)(m0+row)*K + kt*BK + g*8, As + slot*8);
    }
#pragma unroll
    for (int r = 0; r < TN*BK/2048; ++r) {
      int slot = r*256 + tid;
      int row = slot / G, c = slot % G, g = c ^ (row & (G-1));
      gld16(Bw + (size_t)(n0+row)*K + kt*BK + g*8, Bs + slot*8);
    }
    __syncthreads();
#pragma unroll
    for (int ks = 0; ks < BK/32; ++ks) {
      half8 af[MT], bf[NT];
      int kc = ks*4 + lq;
#pragma unroll
      for (int t = 0; t < MT; ++t) {
        int am = wm + t*16 + li;
        af[t] = *(const half8*)&As[am*BK + (kc ^ (am & (G-1)))*8];
      }
#pragma unroll
      for (int t = 0; t < NT; ++t) {
        int bn = wn + t*16 + li;
        bf[t] = *(const half8*)&Bs[bn*BK + (kc ^ (bn & (G-1)))*8];
      }
#pragma unroll
      for (int mt = 0; mt < MT; ++mt)
#pragma unroll
        for (int nt = 0; nt < NT; ++nt)
          acc[mt][nt] = __builtin_amdgcn_mfma_f32_16x16x32_f16(af[mt], bf[nt], acc[mt][nt], 0, 0, 0);
    }
  }

#pragma unroll
  for (int mt = 0; mt < MT; ++mt) {
#pragma unroll
    for (int nt = 0; nt < NT; ++nt) {
      int f = n0 + wn + nt*16 + li;                 // output feature (col, from B)
      float bb = bias[f];
      if (MODE == 0) {
        int which = f >> 10, cc = f & 1023, h = cc >> 6, d = cc & 63;
        int t0 = m0 + wm + mt*16 + lq*4;            // token (row, from A), 4 consecutive
        int b = t0 >> 10, s0 = t0 & 1023;
        if (which == 2) {
          half4v hv;
#pragma unroll
          for (int r = 0; r < 4; ++r) hv[r] = (f16)(acc[mt][nt][r] + bb);
          *(half4v*)&vT[((size_t)((b*HEADS + h)*HD + d))*SEQ + s0] = hv;
        } else {
          unsigned char* dst = (which == 0) ? q8 : k8;
#pragma unroll
          for (int r = 0; r < 4; ++r) {
            float v = acc[mt][nt][r] + bb;
            int u = (int)floorf(v * 16.0f + 128.5f);
            u = u < 0 ? 0 : (u > 255 ? 255 : u);
            dst[((size_t)((b*HEADS + h)*SEQ + s0 + r))*HD + d] = (unsigned char)u;
          }
        }
      } else {
#pragma unroll
        for (int r = 0; r < 4; ++r) {
          int t = m0 + wm + mt*16 + lq*4 + r;
          outp[(size_t)t*DIMC + f] = acc[mt][nt][r] + bb;
        }
      }
    }
  }
}

// ---------------- Laplacian attention + depthwise conv, y16 out ----------------
// R23: attn = exact R19 (proven best: attn 44.5us, total 146.5). R22's kk
// double-buffer + setprio were neutral-to-negative (VGPR 68->84 cost occupancy
// 28->21%). Seven structural variants (R15-R22) all land in 44.5-48.6us ->
// practical plateau for this structure; stop spending rounds here.
__global__ __launch_bounds__(256, 3) void attn_kernel(
    const unsigned char* __restrict__ q8g, const unsigned char* __restrict__ k8g,
    const f16* __restrict__ vTg, const float* __restrict__ dwcw, const float* __restrict__ dwcb,
    f16* __restrict__ y16)
{
  __shared__ unsigned char q8s[32*64];     //  2KB
  __shared__ unsigned char k8s[2][128*64]; // 16KB double-buffered, chunk-swizzled
  __shared__ f16 sfrag[2][8*64*8];         // 16KB double-buffered A-frag scores
  __shared__ float rspart[32*16];          //  2KB
  __shared__ float rowsum[32];             // total ~36.4KB

  const int tid = threadIdx.x;
  const int lin = blockIdx.x + 16 * blockIdx.y;      // 0..1023
  const int bh = (lin & 7) * 4 + ((lin >> 3) & 3);   // XCD-grouped head index
  const int i0 = (lin >> 5) * 32;                    // 32 i-blocks of 32 rows
  const int lane = tid & 63, wave = tid >> 6;
  const int lq = lane >> 4, li = lane & 15;
  const int iL = tid & 15, jt = tid >> 4;       // phase-1 mapping
  const int ksj = jt >> 2, qj = jt & 3;
  const int scs = jt & 3;                       // chunk-swizzle read key

  { // stage q tile (32x64B, waves 0-1) + k8s[0] with chunk swizzle
    if (tid < 128)
      gld16(q8g + ((size_t)(bh*SEQ) + i0)*HD + tid*16, q8s + tid*16);
#pragma unroll
    for (int r = 0; r < 2; ++r) {
      int slot = r*256 + tid;
      int row = slot >> 2, c4 = slot & 3, sc4 = c4 ^ ((row >> 3) & 3);
      gld16(k8g + ((size_t)(bh*SEQ) + row)*HD + sc4*16, k8s[0] + slot*16);
    }
  }
  __syncthreads();

  // q rows {iL, iL+16} into regs (32 u32 — the size that provably stays resident)
  unsigned qr[2][16];
#pragma unroll
  for (int n = 0; n < 2; ++n)
#pragma unroll
    for (int c4 = 0; c4 < 4; ++c4) {
      uint4 t = *(const uint4*)&q8s[(iL + n*16)*64 + c4*16];
      qr[n][c4*4+0] = t.x; qr[n][c4*4+1] = t.y; qr[n][c4*4+2] = t.z; qr[n][c4*4+3] = t.w;
    }

  float rs[2] = {0.f, 0.f};
  floatx4 pacc[2] = {};                  // this wave owns d-strip wave*16..+15
  const f16* vbase = vTg + ((size_t)(bh*HD) + wave*16 + li)*SEQ;

  for (int jb = 0; jb < 8; ++jb) {
    const int j0 = jb * 128;
    const int cur = jb & 1;

    // stage NEXT k tile (consumed in iter jb+1; lands by this iter's barrier)
    if (jb < 7) {
#pragma unroll
      for (int r = 0; r < 2; ++r) {
        int slot = r*256 + tid;
        int row = slot >> 2, c4 = slot & 3, sc4 = c4 ^ ((row >> 3) & 3);
        gld16(k8g + ((size_t)(bh*SEQ) + j0 + 128 + row)*HD + sc4*16,
              k8s[cur ^ 1] + slot*16);
      }
    }
    // issue this iter's V B-frags (global->reg, waited at MFMA use)
    half8 vfrag[4];
#pragma unroll
    for (int ks = 0; ks < 4; ++ks)
      vfrag[ks] = *(const half8*)(vbase + j0 + (ks*4 + lq)*8);

    // ---- phase 1: SAD distances from k8s[cur] (staged last iter) ----
    unsigned sacc[2][8] = {};
#pragma unroll
    for (int c4 = 0; c4 < 4; ++c4) {
      uint4 kk[8];
#pragma unroll
      for (int jj = 0; jj < 8; ++jj)
        kk[jj] = *(const uint4*)&k8s[cur][(jt*8 + jj)*64 + ((c4 ^ scs) << 4)];
#pragma unroll
      for (int n = 0; n < 2; ++n)
#pragma unroll
        for (int jj = 0; jj < 8; ++jj) {
          sacc[n][jj] = sadU8(qr[n][c4*4+0], kk[jj].x, sacc[n][jj]);
          sacc[n][jj] = sadU8(qr[n][c4*4+1], kk[jj].y, sacc[n][jj]);
          sacc[n][jj] = sadU8(qr[n][c4*4+2], kk[jj].z, sacc[n][jj]);
          sacc[n][jj] = sadU8(qr[n][c4*4+3], kk[jj].w, sacc[n][jj]);
        }
    }
    // kern = exp(-dist/16), dist = sad/16  ->  exp2(-sad * log2(e)/256)
#pragma unroll
    for (int n = 0; n < 2; ++n) {
      half8 sv;
#pragma unroll
      for (int jj = 0; jj < 8; ++jj) {
        float sf = exp2f(-0.0056355275f * (float)sacc[n][jj]);
        rs[n] += sf;
        sv[jj] = (f16)sf;
      }
      *(half8*)&sfrag[cur][((n*4 + ksj)*64 + qj*16 + iL)*8] = sv;
    }
    __syncthreads();   // sfrag[cur] ready; k8s[cur^1] landed (vmcnt drain)

    // ---- phase 2: PV via MFMA, wave tile 32i x 16d, B from regs ----
#pragma unroll
    for (int ks = 0; ks < 4; ++ks) {
      half8 a0 = *(const half8*)&sfrag[cur][((0*4 + ks)*64 + lane)*8];
      half8 a1 = *(const half8*)&sfrag[cur][((1*4 + ks)*64 + lane)*8];
      pacc[0] = __builtin_amdgcn_mfma_f32_16x16x32_f16(a0, vfrag[ks], pacc[0], 0, 0, 0);
      pacc[1] = __builtin_amdgcn_mfma_f32_16x16x32_f16(a1, vfrag[ks], pacc[1], 0, 0, 0);
    }
  }

  // rowsum reduction across the 16 j-slices
#pragma unroll
  for (int n = 0; n < 2; ++n) rspart[(iL + n*16)*16 + jt] = rs[n];
  __syncthreads();
  if (tid < 32) {
    float s = 0.f;
#pragma unroll
    for (int t = 0; t < 16; ++t) s += rspart[tid*16 + t];
    rowsum[tid] = s + 1e-6f;
  }
  __syncthreads();

  // epilogue: normalize + depthwise conv + store y16 [b,s,h*64+d]
  const int b = bh >> 4, h = bh & 15;
  {
    int d = wave*16 + li;
    int c = h*64 + d;
    float w0 = dwcw[c*3+0], w1 = dwcw[c*3+1], w2 = dwcw[c*3+2], cb = dwcb[c];
    const f16* vrow = vTg + ((size_t)(bh*HD) + d)*SEQ;
#pragma unroll
    for (int mt = 0; mt < 2; ++mt) {
      int s0 = i0 + mt*16 + lq*4;                  // first of 4 consecutive rows
      float vv[6];
#pragma unroll
      for (int e = 0; e < 6; ++e) {
        int s = s0 - 1 + e;
        vv[e] = (s >= 0 && s < SEQ) ? (float)vrow[s] : 0.f;
      }
#pragma unroll
      for (int r = 0; r < 4; ++r) {
        int ii = mt*16 + lq*4 + r;
        float val = pacc[mt][r] / rowsum[ii];
        val += w0*vv[r] + w1*vv[r+1] + w2*vv[r+2] + cb;
        int s = i0 + ii;
        y16[((size_t)(b*SEQ + s))*DIMC + c] = (f16)val;
      }
    }
  }
}

extern "C" void kernel_launch(void* const* d_in, const int* in_sizes, int n_in,
                              void* d_out, int out_size, void* d_ws, size_t ws_size,
                              hipStream_t stream) {
  const float* x      = (const float*)d_in[0];
  const float* qkv_w  = (const float*)d_in[1];
  const float* qkv_b  = (const float*)d_in[2];
  const float* proj_w = (const float*)d_in[3];
  const float* proj_b = (const float*)d_in[4];
  const float* dwc_w  = (const float*)d_in[5];
  const float* dwc_b  = (const float*)d_in[6];
  float* out = (float*)d_out;

  char* ws = (char*)d_ws;
  f16* x16  = (f16*)(ws);                         //  4 MB
  f16* wq16 = (f16*)(ws + (4ll<<20));             //  6 MB
  f16* wp16 = (f16*)(ws + (10ll<<20));            //  2 MB
  unsigned char* q8 = (unsigned char*)(ws + (12ll<<20));  // 2 MB
  unsigned char* k8 = (unsigned char*)(ws + (14ll<<20));  // 2 MB
  f16* vT   = (f16*)(ws + (16ll<<20));            //  4 MB
  f16* y16  = (f16*)(ws + (20ll<<20));            //  4 MB (total 24 MB)

  cvt_kernel<<<1536, 256, 0, stream>>>(x, qkv_w, proj_w, x16, wq16, wp16);
  // gemm0: 128x128 tile, BK=128 (8 K-iters) — grid 24x16 = 384 blocks (proven)
  gemm_kernel<128,128,128,2,0><<<dim3(24, 16), 256, 0, stream>>>(x16, wq16, qkv_b, q8, k8, vT, nullptr, DIMC);
  // attn: 1024 blocks (32 bh x 32 i-blocks of 32 rows)
  attn_kernel<<<dim3(16, 64), 256, 0, stream>>>(q8, k8, vT, dwc_w, dwc_b, y16);
  // gemm1: 64x64 tile, BK=256 (4 K-iters, 64KB LDS = 2 blocks/CU) — grid 16x32
  gemm_kernel<64,64,256,2,1><<<dim3(16, 32), 256, 0, stream>>>(y16, wp16, proj_b, nullptr, nullptr, nullptr, out, DIMC);
}